// Round 7
// baseline (365.730 us; speedup 1.0000x reference)
//
#include <hip/hip_runtime.h>
#include <hip/hip_cooperative_groups.h>

namespace cg = cooperative_groups;

#define D 64
#define NPB 64
#define THREADS 512
#define CAP 64

__device__ __forceinline__ unsigned short f2bf(float f) {
  unsigned u = __float_as_uint(f);
  return (unsigned short)((u + 0x7FFFu + ((u >> 16) & 1u)) >> 16);
}

// ---------------------------------------------------------------------------
// Cooperative prep: phase A zeroes cnt AND converts x->bf16 (independent,
// no barrier between them); grid.sync(); phase B does the XCD-partitioned
// bucket fill (8 sibling blocks per edge chunk; block commits only dests in
// slab class (dest>>11)&7 == blockIdx&7 -> bucket/cnt lines written by one
// XCD only -> no cross-XCD line bouncing; proven R6).
// ---------------------------------------------------------------------------
__global__ __launch_bounds__(256) void prep_kernel(
    const float* __restrict__ x, const int* __restrict__ ei,
    ushort* __restrict__ xh, int* __restrict__ cnt,
    int* __restrict__ bucket, int n, int e, int qpc) {
  cg::grid_group grid = cg::this_grid();
  const int tid = blockIdx.x * 256 + threadIdx.x;
  const int nth = gridDim.x * 256;

  // ---- phase A: zero cnt + convert ----
  for (int i = tid; i < n; i += nth) cnt[i] = 0;
  const int total4 = n * D / 4;
  for (int i = tid; i < total4; i += nth) {
    float4 v = ((const float4*)x)[i];
    ushort4 h;
    h.x = f2bf(v.x); h.y = f2bf(v.y); h.z = f2bf(v.z); h.w = f2bf(v.w);
    ((ushort4*)xh)[i] = h;
  }
  grid.sync();

  // ---- phase B: XCD-partitioned fill ----
  const int myx = blockIdx.x & 7;
  const int chunk = blockIdx.x >> 3;
  const int quads = e >> 2;
  const int4* row4 = (const int4*)ei;
  const int4* col4 = (const int4*)(ei + e);
  int qend = chunk * qpc + qpc;
  if (qend > quads) qend = quads;
  for (int q = chunk * qpc + threadIdx.x; q < qend; q += 256) {
    int4 r = row4[q];
    int4 c = col4[q];
    if (((c.x >> 11) & 7) == myx) {
      int p = atomicAdd(&cnt[c.x], 1);
      if (p < CAP) bucket[(size_t)c.x * CAP + p] = r.x;
    }
    if (((c.y >> 11) & 7) == myx) {
      int p = atomicAdd(&cnt[c.y], 1);
      if (p < CAP) bucket[(size_t)c.y * CAP + p] = r.y;
    }
    if (((c.z >> 11) & 7) == myx) {
      int p = atomicAdd(&cnt[c.z], 1);
      if (p < CAP) bucket[(size_t)c.z * CAP + p] = r.z;
    }
    if (((c.w >> 11) & 7) == myx) {
      int p = atomicAdd(&cnt[c.w], 1);
      if (p < CAP) bucket[(size_t)c.w * CAP + p] = r.w;
    }
  }
}

// ---------------------------------------------------------------------------
// Fused consume v2: ushort2 gather — 32 lanes cover one 128B bf16 row, so one
// wave-load fetches TWO edge rows (half = lane>>5 selects the edge). Per 2
// edges: 1 bpermute + 1 VMEM + unpack(shl/and) + 2 adds, ~1.5x fewer issue
// slots and 2x fewer VMEM instrs than the scalar-ushort version (R6, 83us,
// VALUBusy 63%). Cross-half merge: one shfl_xor(32) pair per node.
// ---------------------------------------------------------------------------
__global__ __launch_bounds__(THREADS, 8) void fused2_kernel(
    const float* __restrict__ x, const ushort* __restrict__ xh,
    const int* __restrict__ cnt, const float* __restrict__ W,
    const float* __restrict__ b, float* __restrict__ out, int n) {
  __shared__ __align__(16) float xs[NPB * 128];   // 32 KB

  const int lane = threadIdx.x & 63;
  const int wid  = threadIdx.x >> 6;
  const int base = blockIdx.x * NPB;
  const int half = lane >> 5;          // which of the 2 in-flight edges
  const int fl   = lane & 31;          // feature pair: 2*fl, 2*fl+1
  const int* bucket = (const int*)out;
  const ushort* xp = xh + fl * 2;

  for (int m = 0; m < 8; ++m) {
    int nl = wid * 8 + m;
    int node = base + nl;
    if (node < n) {
      int dg = cnt[node];
      int dc = dg < CAP ? dg : CAP;
      int bk = bucket[(size_t)node * CAP + lane];   // coalesced 256B
      float xown = x[(size_t)node * D + lane];
      float sl0 = 0.f, sl1 = 0.f, sl2 = 0.f, sl3 = 0.f;
      float sh0 = 0.f, sh1 = 0.f, sh2 = 0.f, sh3 = 0.f;
      int p = 0;
      for (; p + 8 <= dc; p += 8) {                 // 4 loads (8 edges) in flight
        int a0 = __shfl(bk, p + 0 + half);
        int a1 = __shfl(bk, p + 2 + half);
        int a2 = __shfl(bk, p + 4 + half);
        int a3 = __shfl(bk, p + 6 + half);
        unsigned h0 = *(const unsigned*)(xp + (size_t)a0 * D);
        unsigned h1 = *(const unsigned*)(xp + (size_t)a1 * D);
        unsigned h2 = *(const unsigned*)(xp + (size_t)a2 * D);
        unsigned h3 = *(const unsigned*)(xp + (size_t)a3 * D);
        sl0 += __uint_as_float(h0 << 16);
        sh0 += __uint_as_float(h0 & 0xffff0000u);
        sl1 += __uint_as_float(h1 << 16);
        sh1 += __uint_as_float(h1 & 0xffff0000u);
        sl2 += __uint_as_float(h2 << 16);
        sh2 += __uint_as_float(h2 & 0xffff0000u);
        sl3 += __uint_as_float(h3 << 16);
        sh3 += __uint_as_float(h3 & 0xffff0000u);
      }
      for (; p + 2 <= dc; p += 2) {
        int a = __shfl(bk, p + half);
        unsigned h = *(const unsigned*)(xp + (size_t)a * D);
        sl0 += __uint_as_float(h << 16);
        sh0 += __uint_as_float(h & 0xffff0000u);
      }
      if (p < dc) {                                 // odd leftover: half 0 only
        int a = __shfl(bk, p);
        if (half == 0) {
          unsigned h = *(const unsigned*)(xp + (size_t)a * D);
          sl0 += __uint_as_float(h << 16);
          sh0 += __uint_as_float(h & 0xffff0000u);
        }
      }
      float sl = (sl0 + sl1) + (sl2 + sl3);
      float sh = (sh0 + sh1) + (sh2 + sh3);
      sl += __shfl_xor(sl, 32);
      sh += __shfl_xor(sh, 32);
      float inv = (dg > 0) ? (1.0f / (float)dg) : 0.0f;
      xs[nl * 128 + lane] = xown;
      if (half == 0)
        *(float2*)&xs[nl * 128 + 64 + fl * 2] = make_float2(sl * inv, sh * inv);
    } else {
      xs[nl * 128 + lane]      = 0.0f;
      xs[nl * 128 + 64 + lane] = 0.0f;
    }
  }
  __syncthreads();

  // ---- GEMM [64 x 128] @ [128 x 64], W from global (L1/L2-resident) ----
  const int col = lane;
  float bias = b[col];
  float acc[8];
#pragma unroll
  for (int m = 0; m < 8; ++m) acc[m] = bias;

  for (int k = 0; k < 128; k += 4) {
    float w0 = W[(k + 0) * 64 + col];
    float w1 = W[(k + 1) * 64 + col];
    float w2 = W[(k + 2) * 64 + col];
    float w3 = W[(k + 3) * 64 + col];
#pragma unroll
    for (int m = 0; m < 8; ++m) {
      int nl = wid + m * 8;                         // wave-uniform -> broadcast
      float4 xv = *(const float4*)&xs[nl * 128 + k];
      acc[m] = fmaf(xv.x, w0, acc[m]);
      acc[m] = fmaf(xv.y, w1, acc[m]);
      acc[m] = fmaf(xv.z, w2, acc[m]);
      acc[m] = fmaf(xv.w, w3, acc[m]);
    }
  }

#pragma unroll
  for (int m = 0; m < 8; ++m) {
    int node = base + wid + m * 8;
    if (node < n)
      out[(size_t)node * D + col] = fmaxf(acc[m], 0.0f);
  }
}

// ===========================================================================
// Fallback path (R6 shape, non-cooperative) if ws too small.
// ===========================================================================
__global__ __launch_bounds__(256) void fill_cap_kernel(
    const int* __restrict__ ei, int* __restrict__ cnt,
    int* __restrict__ bucket, int e) {
  int t = blockIdx.x * blockDim.x + threadIdx.x;
  if (t * 4 >= e) return;
  int4 r4 = ((const int4*)ei)[t];
  int4 c4 = ((const int4*)(ei + e))[t];
  int p0 = atomicAdd(&cnt[c4.x], 1);
  int p1 = atomicAdd(&cnt[c4.y], 1);
  int p2 = atomicAdd(&cnt[c4.z], 1);
  int p3 = atomicAdd(&cnt[c4.w], 1);
  if (p0 < CAP) bucket[(size_t)c4.x * CAP + p0] = r4.x;
  if (p1 < CAP) bucket[(size_t)c4.y * CAP + p1] = r4.y;
  if (p2 < CAP) bucket[(size_t)c4.z * CAP + p2] = r4.z;
  if (p3 < CAP) bucket[(size_t)c4.w * CAP + p3] = r4.w;
}

__global__ __launch_bounds__(THREADS, 8) void fused_cap_kernel(
    const float* __restrict__ x, const int* __restrict__ cnt,
    const float* __restrict__ W, const float* __restrict__ b,
    float* __restrict__ out, int n) {
  __shared__ __align__(16) float xs[NPB * 128];
  const int lane = threadIdx.x & 63;
  const int wid  = threadIdx.x >> 6;
  const int base = blockIdx.x * NPB;
  const int* bucket = (const int*)out;

  for (int m = 0; m < 8; ++m) {
    int nl = wid * 8 + m;
    int node = base + nl;
    if (node < n) {
      int dg = cnt[node];
      int dc = dg < CAP ? dg : CAP;
      int bk = bucket[(size_t)node * CAP + lane];
      float xown = x[(size_t)node * D + lane];
      float s0 = 0.f, s1 = 0.f, s2 = 0.f, s3 = 0.f;
      int p = 0;
      for (; p + 4 <= dc; p += 4) {
        int a0 = __shfl(bk, p),     a1 = __shfl(bk, p + 1);
        int a2 = __shfl(bk, p + 2), a3 = __shfl(bk, p + 3);
        s0 += x[(size_t)a0 * D + lane];
        s1 += x[(size_t)a1 * D + lane];
        s2 += x[(size_t)a2 * D + lane];
        s3 += x[(size_t)a3 * D + lane];
      }
      for (; p < dc; ++p)
        s0 += x[(size_t)__shfl(bk, p) * D + lane];
      float sum = (s0 + s1) + (s2 + s3);
      float inv = (dg > 0) ? (1.0f / (float)dg) : 0.0f;
      xs[nl * 128 + lane]      = xown;
      xs[nl * 128 + 64 + lane] = sum * inv;
    } else {
      xs[nl * 128 + lane]      = 0.0f;
      xs[nl * 128 + 64 + lane] = 0.0f;
    }
  }
  __syncthreads();

  const int col = lane;
  float bias = b[col];
  float acc[8];
#pragma unroll
  for (int m = 0; m < 8; ++m) acc[m] = bias;
  for (int k = 0; k < 128; k += 4) {
    float w0 = W[(k + 0) * 64 + col];
    float w1 = W[(k + 1) * 64 + col];
    float w2 = W[(k + 2) * 64 + col];
    float w3 = W[(k + 3) * 64 + col];
#pragma unroll
    for (int m = 0; m < 8; ++m) {
      int nl = wid + m * 8;
      float4 xv = *(const float4*)&xs[nl * 128 + k];
      acc[m] = fmaf(xv.x, w0, acc[m]);
      acc[m] = fmaf(xv.y, w1, acc[m]);
      acc[m] = fmaf(xv.z, w2, acc[m]);
      acc[m] = fmaf(xv.w, w3, acc[m]);
    }
  }
#pragma unroll
  for (int m = 0; m < 8; ++m) {
    int node = base + wid + m * 8;
    if (node < n)
      out[(size_t)node * D + col] = fmaxf(acc[m], 0.0f);
  }
}

extern "C" void kernel_launch(void* const* d_in, const int* in_sizes, int n_in,
                              void* d_out, int out_size, void* d_ws, size_t ws_size,
                              hipStream_t stream) {
  const float* x = (const float*)d_in[0];
  const int* ei = (const int*)d_in[1];
  const float* W = (const float*)d_in[2];
  const float* b = (const float*)d_in[3];
  float* out = (float*)d_out;

  int n = in_sizes[0] / D;            // 100000
  int e = in_sizes[1] / 2;            // 1250000
  int nblocks = (n + NPB - 1) / NPB;  // 1563

  size_t xh_bytes = (size_t)n * D * sizeof(ushort);       // 12.8 MB
  size_t need = xh_bytes + (size_t)n * sizeof(int) + 256;

  if (ws_size >= need && (e & 3) == 0 && n <= (1 << 17)) {
    ushort* xh = (ushort*)d_ws;
    int* cnt = (int*)((char*)d_ws + ((xh_bytes + 255) & ~(size_t)255));

    // size cooperative grid from occupancy (host query, capture-safe)
    int occ = 8, ncu = 256;
    hipOccupancyMaxActiveBlocksPerMultiprocessor(&occ, prep_kernel, 256, 0);
    hipDeviceGetAttribute(&ncu, hipDeviceAttributeMultiprocessorCount, 0);
    long long cap = (long long)occ * ncu;
    int grid = (int)(cap < 2048 ? cap : 2048);
    grid &= ~7;                        // multiple of 8 for XCD classes
    if (grid < 8) grid = 8;

    int quads = e >> 2;
    int nchunks = grid >> 3;
    int qpc = (quads + nchunks - 1) / nchunks;

    void* args[] = {(void*)&x, (void*)&ei, (void*)&xh, (void*)&cnt,
                    (void*)&d_out, (void*)&n, (void*)&e, (void*)&qpc};
    hipLaunchCooperativeKernel((void*)prep_kernel, dim3(grid), dim3(256),
                               args, 0, stream);

    fused2_kernel<<<nblocks, THREADS, 0, stream>>>(x, xh, cnt, W, b, out, n);
  } else {
    int* cnt = (int*)d_ws;
    hipMemsetAsync(cnt, 0, (size_t)n * sizeof(int), stream);
    int quads = e / 4;
    fill_cap_kernel<<<(quads + 255) / 256, 256, 0, stream>>>(ei, cnt, (int*)d_out, e);
    fused_cap_kernel<<<nblocks, THREADS, 0, stream>>>(x, cnt, W, b, out, n);
  }
}

// Round 8
// 266.808 us; speedup vs baseline: 1.3708x; 1.3708x over previous
//
#include <hip/hip_runtime.h>

#define D 64
#define NPB 64
#define GROUPS_MAX 112       // dest-groups of 1024 nodes (n <= 114688)
#define STAGECAP 40          // LDS staged entries per group per block
#define BINCAP 16384         // global bin capacity (mean 12800, +31 sigma)
#define LISTCAP 48           // per-node neighbor list (Poisson 12.5, +10 sigma)
#define CAP 64               // last-resort fallback path

__device__ __forceinline__ unsigned short f2bf(float f) {
  unsigned u = __float_as_uint(f);
  return (unsigned short)((u + 0x7FFFu + ((u >> 16) & 1u)) >> 16);
}
__device__ __forceinline__ float bf2f(unsigned short h) {
  return __uint_as_float(((unsigned)h) << 16);
}

// ---------------------------------------------------------------------------
// x (fp32) -> xh (bf16). Streaming, ~8 us (proven R6).
// ---------------------------------------------------------------------------
__global__ __launch_bounds__(256) void cvt_kernel(
    const float* __restrict__ x, ushort* __restrict__ xh, int total4) {
  int t = blockIdx.x * blockDim.x + threadIdx.x;
  if (t >= total4) return;
  float4 v = ((const float4*)x)[t];
  ushort4 h;
  h.x = f2bf(v.x); h.y = f2bf(v.y); h.z = f2bf(v.z); h.w = f2bf(v.w);
  ((ushort4*)xh)[t] = h;
}

// ---------------------------------------------------------------------------
// Fill: LDS-staged binning with FULL-LINE flushes. Edges are staged in
// per-block LDS buffers (one per 1024-node dest group); when a group's stage
// reaches >=16 entries the owner wave reserves space with ONE global cursor
// atomic and writes a 64B-aligned, 16-entry-multiple coalesced burst.
// This kills the 75 MB line-writeback amp of scattered 4B stores
// (R3/R6/R7 evidence: WRITE_SIZE ~= edges * 64B regardless of layout).
// Entry = src | (dst & 1023) << 17   (src < 2^17).
// gcur cursors padded to 64B (16 ints) to avoid cursor-line contention (R4).
// ---------------------------------------------------------------------------
__global__ __launch_bounds__(512) void fill_bin_kernel(
    const int* __restrict__ ei, int* __restrict__ gcur,
    int* __restrict__ bins, int e, int groups, int tb) {
  __shared__ int staged[GROUPS_MAX * STAGECAP];   // 17.5 KB
  __shared__ int scur[GROUPS_MAX];

  const int tid = threadIdx.x;
  const int lane = tid & 63;
  const int wid = tid >> 6;

  for (int i = tid; i < groups; i += 512) scur[i] = 0;
  __syncthreads();

  for (int bt = blockIdx.x; bt < tb; bt += gridDim.x) {
    // ---- append ----
    int idx = bt * 512 + tid;
    if (idx < e) {
      int r = ei[idx];
      int c = ei[e + idx];
      int bin = c >> 10;
      int entry = r | ((c & 1023) << 17);
      int slot = atomicAdd(&scur[bin], 1);
      if (slot < STAGECAP) {
        staged[bin * STAGECAP + slot] = entry;
      } else {                                    // rare staging overflow
        int gs = atomicAdd(&gcur[bin * 16], 1);
        if (gs < BINCAP) bins[(size_t)bin * BINCAP + gs] = entry;
      }
    }
    __syncthreads();
    // ---- flush full lines (wave wid owns bins with bin%8==wid) ----
    for (int bin = wid; bin < groups; bin += 8) {
      int tot = scur[bin];
      if (tot > STAGECAP) tot = STAGECAP;
      int fl = tot & ~15;
      if (fl > 0) {
        int base;
        if (lane == 0) base = atomicAdd(&gcur[bin * 16], fl);
        base = __shfl(base, 0);
        int v = 0;
        if (lane < fl) v = staged[bin * STAGECAP + lane];
        if (lane < fl && base + lane < BINCAP)
          bins[(size_t)bin * BINCAP + base + lane] = v;   // 64B-aligned burst
        int rem = tot - fl;
        int vr = (lane < rem) ? staged[bin * STAGECAP + fl + lane] : 0;
        if (lane < rem) staged[bin * STAGECAP + lane] = vr;
        if (lane == 0) scur[bin] = rem;
      }
    }
    __syncthreads();
  }
  // ---- drain remainders (partial lines, ~7 entries/bin avg: small) ----
  for (int bin = wid; bin < groups; bin += 8) {
    int tot = scur[bin];
    if (tot > STAGECAP) tot = STAGECAP;
    if (tot > 0) {
      int base;
      if (lane == 0) base = atomicAdd(&gcur[bin * 16], tot);
      base = __shfl(base, 0);
      if (lane < tot) {
        int v = staged[bin * STAGECAP + lane];
        if (base + lane < BINCAP)
          bins[(size_t)bin * BINCAP + base + lane] = v;
      }
    }
  }
}

// ---------------------------------------------------------------------------
// Fused consume: block b (64 nodes) scans group g=b>>4's bin, filters its
// 16th sub-range into per-node LDS lists, then R6's proven register gather
// (bf16 or fp32) -> LDS tile -> broadcast GEMM. d_out untouched until store.
// ---------------------------------------------------------------------------
template <bool BF16>
__global__ __launch_bounds__(512) void fused_bin_kernel(
    const float* __restrict__ x, const ushort* __restrict__ xh,
    const int* __restrict__ gcur, const int* __restrict__ bins,
    const float* __restrict__ W, const float* __restrict__ b,
    float* __restrict__ out, int n) {
  __shared__ __align__(16) float xs[NPB * 128];   // 32 KB
  __shared__ int lst[NPB * LISTCAP];              // 12 KB
  __shared__ int lcur[NPB];

  const int lane = threadIdx.x & 63;
  const int wid  = threadIdx.x >> 6;
  const int base = blockIdx.x * NPB;

  // phase 0: own rows + zero acc half + zero list cursors
  if (threadIdx.x < NPB) lcur[threadIdx.x] = 0;
#pragma unroll
  for (int m = 0; m < 8; ++m) {
    int nl = wid * 8 + m;
    int node = base + nl;
    xs[nl * 128 + 64 + lane] = 0.0f;
    xs[nl * 128 + lane] = (node < n) ? x[(size_t)node * D + lane] : 0.0f;
  }
  __syncthreads();

  // phase 1: scan group bin, filter sub-range, build per-node lists
  const int g = blockIdx.x >> 4;
  const int sub = blockIdx.x & 15;
  int Lg = gcur[g * 16];
  if (Lg > BINCAP) Lg = BINCAP;
  const int* bp = bins + (size_t)g * BINCAP;
  for (int i = threadIdx.x; i < Lg; i += 512) {
    int entry = bp[i];
    if (((entry >> 23) & 15) == sub) {
      int nl = (entry >> 17) & 63;
      int slot = atomicAdd(&lcur[nl], 1);
      if (slot < LISTCAP) lst[nl * LISTCAP + slot] = entry & 0x1FFFF;
    }
  }
  __syncthreads();

  // phase 2: register gather (R6-proven 8-deep)
  for (int m = 0; m < 8; ++m) {
    int nl = wid * 8 + m;
    int node = base + nl;
    if (node < n) {
      int dg = lcur[nl];
      if (dg > LISTCAP) dg = LISTCAP;
      int bk = (lane < LISTCAP) ? lst[nl * LISTCAP + lane] : 0;
      float s0 = 0.f, s1 = 0.f, s2 = 0.f, s3 = 0.f;
      float s4 = 0.f, s5 = 0.f, s6 = 0.f, s7 = 0.f;
      int p = 0;
      for (; p + 8 <= dg; p += 8) {               // 8 loads in flight
        int a0 = __shfl(bk, p),     a1 = __shfl(bk, p + 1);
        int a2 = __shfl(bk, p + 2), a3 = __shfl(bk, p + 3);
        int a4 = __shfl(bk, p + 4), a5 = __shfl(bk, p + 5);
        int a6 = __shfl(bk, p + 6), a7 = __shfl(bk, p + 7);
        if (BF16) {
          s0 += bf2f(xh[(size_t)a0 * D + lane]);
          s1 += bf2f(xh[(size_t)a1 * D + lane]);
          s2 += bf2f(xh[(size_t)a2 * D + lane]);
          s3 += bf2f(xh[(size_t)a3 * D + lane]);
          s4 += bf2f(xh[(size_t)a4 * D + lane]);
          s5 += bf2f(xh[(size_t)a5 * D + lane]);
          s6 += bf2f(xh[(size_t)a6 * D + lane]);
          s7 += bf2f(xh[(size_t)a7 * D + lane]);
        } else {
          s0 += x[(size_t)a0 * D + lane];
          s1 += x[(size_t)a1 * D + lane];
          s2 += x[(size_t)a2 * D + lane];
          s3 += x[(size_t)a3 * D + lane];
          s4 += x[(size_t)a4 * D + lane];
          s5 += x[(size_t)a5 * D + lane];
          s6 += x[(size_t)a6 * D + lane];
          s7 += x[(size_t)a7 * D + lane];
        }
      }
      for (; p + 4 <= dg; p += 4) {
        int a0 = __shfl(bk, p),     a1 = __shfl(bk, p + 1);
        int a2 = __shfl(bk, p + 2), a3 = __shfl(bk, p + 3);
        if (BF16) {
          s0 += bf2f(xh[(size_t)a0 * D + lane]);
          s1 += bf2f(xh[(size_t)a1 * D + lane]);
          s2 += bf2f(xh[(size_t)a2 * D + lane]);
          s3 += bf2f(xh[(size_t)a3 * D + lane]);
        } else {
          s0 += x[(size_t)a0 * D + lane];
          s1 += x[(size_t)a1 * D + lane];
          s2 += x[(size_t)a2 * D + lane];
          s3 += x[(size_t)a3 * D + lane];
        }
      }
      for (; p < dg; ++p) {
        int a = __shfl(bk, p);
        s0 += BF16 ? bf2f(xh[(size_t)a * D + lane]) : x[(size_t)a * D + lane];
      }
      float sum = ((s0 + s1) + (s2 + s3)) + ((s4 + s5) + (s6 + s7));
      float inv = (dg > 0) ? (1.0f / (float)dg) : 0.0f;
      xs[nl * 128 + 64 + lane] = sum * inv;
    }
  }
  __syncthreads();

  // phase 3: GEMM [64 x 128] @ [128 x 64], W from global (L1/L2-resident)
  const int col = lane;
  float bias = b[col];
  float acc[8];
#pragma unroll
  for (int m = 0; m < 8; ++m) acc[m] = bias;

  for (int k = 0; k < 128; k += 4) {
    float w0 = W[(k + 0) * 64 + col];
    float w1 = W[(k + 1) * 64 + col];
    float w2 = W[(k + 2) * 64 + col];
    float w3 = W[(k + 3) * 64 + col];
#pragma unroll
    for (int m = 0; m < 8; ++m) {
      int nl = wid + m * 8;                       // wave-uniform -> broadcast
      float4 xv = *(const float4*)&xs[nl * 128 + k];
      acc[m] = fmaf(xv.x, w0, acc[m]);
      acc[m] = fmaf(xv.y, w1, acc[m]);
      acc[m] = fmaf(xv.z, w2, acc[m]);
      acc[m] = fmaf(xv.w, w3, acc[m]);
    }
  }

#pragma unroll
  for (int m = 0; m < 8; ++m) {
    int node = base + wid + m * 8;
    if (node < n)
      out[(size_t)node * D + col] = fmaxf(acc[m], 0.0f);
  }
}

// ===========================================================================
// Last-resort fallback (R3 shape, proven): bucket in d_out, cnt in ws.
// ===========================================================================
__global__ __launch_bounds__(256) void fill_cap_kernel(
    const int* __restrict__ ei, int* __restrict__ cnt,
    int* __restrict__ bucket, int e) {
  int t = blockIdx.x * blockDim.x + threadIdx.x;
  if (t >= e) return;
  int r = ei[t], c = ei[e + t];
  int p = atomicAdd(&cnt[c], 1);
  if (p < CAP) bucket[(size_t)c * CAP + p] = r;
}

__global__ __launch_bounds__(512) void fused_cap_kernel(
    const float* __restrict__ x, const int* __restrict__ cnt,
    const float* __restrict__ W, const float* __restrict__ b,
    float* __restrict__ out, int n) {
  __shared__ __align__(16) float xs[NPB * 128];
  const int lane = threadIdx.x & 63;
  const int wid  = threadIdx.x >> 6;
  const int base = blockIdx.x * NPB;
  const int* bucket = (const int*)out;
  for (int m = 0; m < 8; ++m) {
    int nl = wid * 8 + m;
    int node = base + nl;
    if (node < n) {
      int dg = cnt[node];
      int dc = dg < CAP ? dg : CAP;
      int bk = bucket[(size_t)node * CAP + lane];
      float s0 = 0.f, s1 = 0.f, s2 = 0.f, s3 = 0.f;
      int p = 0;
      for (; p + 4 <= dc; p += 4) {
        int a0 = __shfl(bk, p),     a1 = __shfl(bk, p + 1);
        int a2 = __shfl(bk, p + 2), a3 = __shfl(bk, p + 3);
        s0 += x[(size_t)a0 * D + lane];
        s1 += x[(size_t)a1 * D + lane];
        s2 += x[(size_t)a2 * D + lane];
        s3 += x[(size_t)a3 * D + lane];
      }
      for (; p < dc; ++p) s0 += x[(size_t)__shfl(bk, p) * D + lane];
      float inv = (dg > 0) ? (1.0f / (float)dg) : 0.0f;
      xs[nl * 128 + lane] = x[(size_t)node * D + lane];
      xs[nl * 128 + 64 + lane] = ((s0 + s1) + (s2 + s3)) * inv;
    } else {
      xs[nl * 128 + lane] = 0.0f;
      xs[nl * 128 + 64 + lane] = 0.0f;
    }
  }
  __syncthreads();
  const int col = lane;
  float acc[8];
#pragma unroll
  for (int m = 0; m < 8; ++m) acc[m] = b[col];
  for (int k = 0; k < 128; k += 4) {
    float w0 = W[(k + 0) * 64 + col], w1 = W[(k + 1) * 64 + col];
    float w2 = W[(k + 2) * 64 + col], w3 = W[(k + 3) * 64 + col];
#pragma unroll
    for (int m = 0; m < 8; ++m) {
      int nl = wid + m * 8;
      float4 xv = *(const float4*)&xs[nl * 128 + k];
      acc[m] = fmaf(xv.x, w0, fmaf(xv.y, w1, fmaf(xv.z, w2, fmaf(xv.w, w3, acc[m]))));
    }
  }
#pragma unroll
  for (int m = 0; m < 8; ++m) {
    int node = base + wid + m * 8;
    if (node < n) out[(size_t)node * D + col] = fmaxf(acc[m], 0.0f);
  }
}

extern "C" void kernel_launch(void* const* d_in, const int* in_sizes, int n_in,
                              void* d_out, int out_size, void* d_ws, size_t ws_size,
                              hipStream_t stream) {
  const float* x = (const float*)d_in[0];
  const int* ei = (const int*)d_in[1];
  const float* W = (const float*)d_in[2];
  const float* b = (const float*)d_in[3];
  float* out = (float*)d_out;

  int n = in_sizes[0] / D;             // 100000
  int e = in_sizes[1] / 2;             // 1250000
  int nblocks = (n + NPB - 1) / NPB;   // 1563
  int groups = (n + 1023) >> 10;       // 98
  int tb = (e + 511) / 512;            // 2442

  size_t gcur_bytes = (size_t)GROUPS_MAX * 16 * sizeof(int);           // 7 KB
  size_t bins_bytes = (size_t)groups * BINCAP * sizeof(int);           // 6.42 MB
  size_t xh_bytes   = (size_t)n * D * sizeof(ushort);                  // 12.8 MB
  size_t need_f32 = gcur_bytes + bins_bytes + 256;
  size_t need_bf  = need_f32 + xh_bytes + 256;

  bool ok = (groups <= GROUPS_MAX) && (n <= (1 << 17));

  if (ok && ws_size >= need_f32) {
    int* gcur = (int*)d_ws;
    int* bins = (int*)((char*)d_ws + ((gcur_bytes + 255) & ~(size_t)255));
    bool bf16 = (ws_size >= need_bf);
    ushort* xh = (ushort*)((char*)bins + ((bins_bytes + 255) & ~(size_t)255));

    hipMemsetAsync(gcur, 0, gcur_bytes, stream);
    if (bf16) {
      int total4 = n * D / 4;
      cvt_kernel<<<(total4 + 255) / 256, 256, 0, stream>>>(x, xh, total4);
    }
    fill_bin_kernel<<<256, 512, 0, stream>>>(ei, gcur, bins, e, groups, tb);
    if (bf16)
      fused_bin_kernel<true><<<nblocks, 512, 0, stream>>>(x, xh, gcur, bins, W, b, out, n);
    else
      fused_bin_kernel<false><<<nblocks, 512, 0, stream>>>(x, xh, gcur, bins, W, b, out, n);
  } else {
    int* cnt = (int*)d_ws;
    hipMemsetAsync(cnt, 0, (size_t)n * sizeof(int), stream);
    fill_cap_kernel<<<(e + 255) / 256, 256, 0, stream>>>(ei, cnt, (int*)d_out, e);
    fused_cap_kernel<<<nblocks, 512, 0, stream>>>(x, cnt, W, b, out, n);
  }
}

// Round 10
// 209.114 us; speedup vs baseline: 1.7489x; 1.2759x over previous
//
#include <hip/hip_runtime.h>

#define D 64
#define NPB 64
#define THREADS 512
#define CAP 64

typedef int v4i __attribute__((ext_vector_type(4)));   // nt-load-compatible int4

__device__ __forceinline__ unsigned short f2bf(float f) {
  unsigned u = __float_as_uint(f);
  return (unsigned short)((u + 0x7FFFu + ((u >> 16) & 1u)) >> 16);
}
__device__ __forceinline__ float bf2f(unsigned short h) {
  return __uint_as_float(((unsigned)h) << 16);
}

// ---------------------------------------------------------------------------
// Prep: zero cnt + convert x->bf16 in one dispatch (independent jobs; the
// kernel boundary orders them before fill).
// ---------------------------------------------------------------------------
__global__ __launch_bounds__(256) void prep0_kernel(
    const float* __restrict__ x, ushort* __restrict__ xh,
    int* __restrict__ cnt, int n, int total4) {
  int t = blockIdx.x * blockDim.x + threadIdx.x;
  int nth = gridDim.x * blockDim.x;
  for (int i = t; i < n; i += nth) cnt[i] = 0;
  for (int i = t; i < total4; i += nth) {
    float4 v = ((const float4*)x)[i];
    ushort4 h;
    h.x = f2bf(v.x); h.y = f2bf(v.y); h.z = f2bf(v.z); h.w = f2bf(v.w);
    ((ushort4*)xh)[i] = h;
  }
}

// ---------------------------------------------------------------------------
// XCD-partitioned bucket fill (R6-proven) + NON-TEMPORAL edge loads.
// R7 evidence: partitioning alone left WRITE_SIZE at 72 MB because streaming
// the full edge list through each XCD's 4 MB L2 evicts dirty bucket lines
// before they fill (~12.5 appends/line). nt loads keep the ~3.2 MB dirty
// slab resident -> writeback ~= payload.
// Bucket entries are PRE-SCALED (src*64) so the consume's address math is
// a single add per edge-lane.
// ---------------------------------------------------------------------------
__global__ __launch_bounds__(256) void fill_xcd_kernel(
    const int* __restrict__ ei, int* __restrict__ cnt,
    int* __restrict__ bucket, int e, int qpc) {
  const int myx = blockIdx.x & 7;
  const int chunk = blockIdx.x >> 3;
  const int quads = e >> 2;
  const v4i* row4 = (const v4i*)ei;
  const v4i* col4 = (const v4i*)(ei + e);
  int qend = chunk * qpc + qpc;
  if (qend > quads) qend = quads;
  for (int q = chunk * qpc + threadIdx.x; q < qend; q += 256) {
    v4i r = __builtin_nontemporal_load(&row4[q]);
    v4i c = __builtin_nontemporal_load(&col4[q]);
    if (((c.x >> 11) & 7) == myx) {
      int p = atomicAdd(&cnt[c.x], 1);
      if (p < CAP) bucket[(size_t)c.x * CAP + p] = r.x * D;
    }
    if (((c.y >> 11) & 7) == myx) {
      int p = atomicAdd(&cnt[c.y], 1);
      if (p < CAP) bucket[(size_t)c.y * CAP + p] = r.y * D;
    }
    if (((c.z >> 11) & 7) == myx) {
      int p = atomicAdd(&cnt[c.z], 1);
      if (p < CAP) bucket[(size_t)c.z * CAP + p] = r.z * D;
    }
    if (((c.w >> 11) & 7) == myx) {
      int p = atomicAdd(&cnt[c.w], 1);
      if (p < CAP) bucket[(size_t)c.w * CAP + p] = r.w * D;
    }
  }
}

// ---------------------------------------------------------------------------
// Fused consume (R6-proven shape): wave per 8 nodes, lane = feature,
// 8-deep unrolled register-sum bf16 gather (pre-scaled offsets: addr = one
// add) -> fp32 LDS tile -> broadcast GEMM (W from global, L1/L2-resident).
// ---------------------------------------------------------------------------
__global__ __launch_bounds__(THREADS, 8) void fused_bf_kernel(
    const float* __restrict__ x, const ushort* __restrict__ xh,
    const int* __restrict__ cnt, const float* __restrict__ W,
    const float* __restrict__ b, float* __restrict__ out, int n) {
  __shared__ __align__(16) float xs[NPB * 128];   // 32 KB

  const int lane = threadIdx.x & 63;
  const int wid  = threadIdx.x >> 6;
  const int base = blockIdx.x * NPB;
  const int* bucket = (const int*)out;
  const ushort* xpl = xh + lane;

  for (int m = 0; m < 8; ++m) {
    int nl = wid * 8 + m;
    int node = base + nl;
    if (node < n) {
      int dg = cnt[node];
      int dc = dg < CAP ? dg : CAP;
      int bk = bucket[(size_t)node * CAP + lane];   // coalesced 256B
      float xown = x[(size_t)node * D + lane];
      float s0 = 0.f, s1 = 0.f, s2 = 0.f, s3 = 0.f;
      float s4 = 0.f, s5 = 0.f, s6 = 0.f, s7 = 0.f;
      int p = 0;
      for (; p + 8 <= dc; p += 8) {                 // 8 loads in flight
        int a0 = __shfl(bk, p),     a1 = __shfl(bk, p + 1);
        int a2 = __shfl(bk, p + 2), a3 = __shfl(bk, p + 3);
        int a4 = __shfl(bk, p + 4), a5 = __shfl(bk, p + 5);
        int a6 = __shfl(bk, p + 6), a7 = __shfl(bk, p + 7);
        s0 += bf2f(xpl[a0]); s1 += bf2f(xpl[a1]);
        s2 += bf2f(xpl[a2]); s3 += bf2f(xpl[a3]);
        s4 += bf2f(xpl[a4]); s5 += bf2f(xpl[a5]);
        s6 += bf2f(xpl[a6]); s7 += bf2f(xpl[a7]);
      }
      for (; p + 4 <= dc; p += 4) {
        int a0 = __shfl(bk, p),     a1 = __shfl(bk, p + 1);
        int a2 = __shfl(bk, p + 2), a3 = __shfl(bk, p + 3);
        s0 += bf2f(xpl[a0]); s1 += bf2f(xpl[a1]);
        s2 += bf2f(xpl[a2]); s3 += bf2f(xpl[a3]);
      }
      for (; p < dc; ++p)
        s0 += bf2f(xpl[__shfl(bk, p)]);
      float sum = ((s0 + s1) + (s2 + s3)) + ((s4 + s5) + (s6 + s7));
      float inv = (dg > 0) ? (1.0f / (float)dg) : 0.0f;
      xs[nl * 128 + lane]      = xown;
      xs[nl * 128 + 64 + lane] = sum * inv;
    } else {
      xs[nl * 128 + lane]      = 0.0f;
      xs[nl * 128 + 64 + lane] = 0.0f;
    }
  }
  __syncthreads();

  const int col = lane;
  float bias = b[col];
  float acc[8];
#pragma unroll
  for (int m = 0; m < 8; ++m) acc[m] = bias;

  for (int k = 0; k < 128; k += 4) {
    float w0 = W[(k + 0) * 64 + col];
    float w1 = W[(k + 1) * 64 + col];
    float w2 = W[(k + 2) * 64 + col];
    float w3 = W[(k + 3) * 64 + col];
#pragma unroll
    for (int m = 0; m < 8; ++m) {
      int nl = wid + m * 8;                         // wave-uniform -> broadcast
      float4 xv = *(const float4*)&xs[nl * 128 + k];
      acc[m] = fmaf(xv.x, w0, acc[m]);
      acc[m] = fmaf(xv.y, w1, acc[m]);
      acc[m] = fmaf(xv.z, w2, acc[m]);
      acc[m] = fmaf(xv.w, w3, acc[m]);
    }
  }

#pragma unroll
  for (int m = 0; m < 8; ++m) {
    int node = base + wid + m * 8;
    if (node < n)
      out[(size_t)node * D + col] = fmaxf(acc[m], 0.0f);
  }
}

// ===========================================================================
// Fallback path (R3-proven) if ws can't hold xh + cnt.
// ===========================================================================
__global__ __launch_bounds__(256) void fill_cap_kernel(
    const int* __restrict__ ei, int* __restrict__ cnt,
    int* __restrict__ bucket, int e) {
  int t = blockIdx.x * blockDim.x + threadIdx.x;
  if (t * 4 >= e) return;
  int4 r4 = ((const int4*)ei)[t];
  int4 c4 = ((const int4*)(ei + e))[t];
  int p0 = atomicAdd(&cnt[c4.x], 1);
  int p1 = atomicAdd(&cnt[c4.y], 1);
  int p2 = atomicAdd(&cnt[c4.z], 1);
  int p3 = atomicAdd(&cnt[c4.w], 1);
  if (p0 < CAP) bucket[(size_t)c4.x * CAP + p0] = r4.x;
  if (p1 < CAP) bucket[(size_t)c4.y * CAP + p1] = r4.y;
  if (p2 < CAP) bucket[(size_t)c4.z * CAP + p2] = r4.z;
  if (p3 < CAP) bucket[(size_t)c4.w * CAP + p3] = r4.w;
}

__global__ __launch_bounds__(THREADS, 8) void fused_cap_kernel(
    const float* __restrict__ x, const int* __restrict__ cnt,
    const float* __restrict__ W, const float* __restrict__ b,
    float* __restrict__ out, int n) {
  __shared__ __align__(16) float xs[NPB * 128];
  const int lane = threadIdx.x & 63;
  const int wid  = threadIdx.x >> 6;
  const int base = blockIdx.x * NPB;
  const int* bucket = (const int*)out;

  for (int m = 0; m < 8; ++m) {
    int nl = wid * 8 + m;
    int node = base + nl;
    if (node < n) {
      int dg = cnt[node];
      int dc = dg < CAP ? dg : CAP;
      int bk = bucket[(size_t)node * CAP + lane];
      float xown = x[(size_t)node * D + lane];
      float s0 = 0.f, s1 = 0.f, s2 = 0.f, s3 = 0.f;
      int p = 0;
      for (; p + 4 <= dc; p += 4) {
        int a0 = __shfl(bk, p),     a1 = __shfl(bk, p + 1);
        int a2 = __shfl(bk, p + 2), a3 = __shfl(bk, p + 3);
        s0 += x[(size_t)a0 * D + lane];
        s1 += x[(size_t)a1 * D + lane];
        s2 += x[(size_t)a2 * D + lane];
        s3 += x[(size_t)a3 * D + lane];
      }
      for (; p < dc; ++p)
        s0 += x[(size_t)__shfl(bk, p) * D + lane];
      float sum = (s0 + s1) + (s2 + s3);
      float inv = (dg > 0) ? (1.0f / (float)dg) : 0.0f;
      xs[nl * 128 + lane]      = xown;
      xs[nl * 128 + 64 + lane] = sum * inv;
    } else {
      xs[nl * 128 + lane]      = 0.0f;
      xs[nl * 128 + 64 + lane] = 0.0f;
    }
  }
  __syncthreads();

  const int col = lane;
  float bias = b[col];
  float acc[8];
#pragma unroll
  for (int m = 0; m < 8; ++m) acc[m] = bias;
  for (int k = 0; k < 128; k += 4) {
    float w0 = W[(k + 0) * 64 + col];
    float w1 = W[(k + 1) * 64 + col];
    float w2 = W[(k + 2) * 64 + col];
    float w3 = W[(k + 3) * 64 + col];
#pragma unroll
    for (int m = 0; m < 8; ++m) {
      int nl = wid + m * 8;
      float4 xv = *(const float4*)&xs[nl * 128 + k];
      acc[m] = fmaf(xv.x, w0, acc[m]);
      acc[m] = fmaf(xv.y, w1, acc[m]);
      acc[m] = fmaf(xv.z, w2, acc[m]);
      acc[m] = fmaf(xv.w, w3, acc[m]);
    }
  }
#pragma unroll
  for (int m = 0; m < 8; ++m) {
    int node = base + wid + m * 8;
    if (node < n)
      out[(size_t)node * D + col] = fmaxf(acc[m], 0.0f);
  }
}

extern "C" void kernel_launch(void* const* d_in, const int* in_sizes, int n_in,
                              void* d_out, int out_size, void* d_ws, size_t ws_size,
                              hipStream_t stream) {
  const float* x = (const float*)d_in[0];
  const int* ei = (const int*)d_in[1];
  const float* W = (const float*)d_in[2];
  const float* b = (const float*)d_in[3];
  float* out = (float*)d_out;

  int n = in_sizes[0] / D;            // 100000
  int e = in_sizes[1] / 2;            // 1250000
  int nblocks = (n + NPB - 1) / NPB;  // 1563

  size_t xh_bytes = (size_t)n * D * sizeof(ushort);       // 12.8 MB
  size_t need = xh_bytes + (size_t)n * sizeof(int) + 256;

  if (ws_size >= need && (e & 3) == 0 && n <= (1 << 17)) {
    ushort* xh = (ushort*)d_ws;
    int* cnt = (int*)((char*)d_ws + ((xh_bytes + 255) & ~(size_t)255));

    int total4 = n * D / 4;
    prep0_kernel<<<2048, 256, 0, stream>>>(x, xh, cnt, n, total4);

    int quads = e >> 2;                       // 312500
    int qpc = (quads + 255) / 256;            // quads per chunk (256 chunks)
    fill_xcd_kernel<<<256 * 8, 256, 0, stream>>>(ei, cnt, (int*)d_out, e, qpc);

    fused_bf_kernel<<<nblocks, THREADS, 0, stream>>>(x, xh, cnt, W, b, out, n);
  } else {
    int* cnt = (int*)d_ws;
    (void)hipMemsetAsync(cnt, 0, (size_t)n * sizeof(int), stream);
    int quads = e / 4;
    fill_cap_kernel<<<(quads + 255) / 256, 256, 0, stream>>>(ei, cnt, (int*)d_out, e);
    fused_cap_kernel<<<nblocks, THREADS, 0, stream>>>(x, cnt, W, b, out, n);
  }
}